// Round 14
// baseline (267.787 us; speedup 1.0000x reference)
//
#include <hip/hip_runtime.h>

#define TPB 256

typedef _Float16 hf2 __attribute__((ext_vector_type(2)));

__device__ __forceinline__ hf2 as_h2(unsigned u) { return __builtin_bit_cast(hf2, u); }
__device__ __forceinline__ unsigned pk2h(float a, float b) {
    unsigned la = (unsigned)__builtin_bit_cast(unsigned short, (_Float16)a);
    unsigned hb = (unsigned)__builtin_bit_cast(unsigned short, (_Float16)b);
    return la | (hb << 16);
}
#define FDOT2(w, x, acc) __builtin_amdgcn_fdot2(as_h2(w), as_h2(x), (acc), false)
#define UPa(u) ((float)(as_h2(u).x))
#define UPb(u) ((float)(as_h2(u).y))

// All-DPP cross-lane sums (VALU pipe): xor1=quad_perm 0xB1, xor2=0x4E,
// row_ror:4=0x124, row_ror:8=0x128 (validated r12: rotations on
// quad-uniform values give every lane the full 16-lane sum).
#define DPPADD(v, CTRL) ((v) + __int_as_float(__builtin_amdgcn_update_dpp( \
    0, __float_as_int(v), (CTRL), 0xF, 0xF, false)))
#define RED4(v)  { v = DPPADD(v, 0xB1); v = DPPADD(v, 0x4E); }
#define RED16(v) { v = DPPADD(v, 0xB1); v = DPPADD(v, 0x4E); \
                   v = DPPADD(v, 0x124); v = DPPADD(v, 0x128); }
#define RED64(v) { v += __shfl_xor(v,32,64); v += __shfl_xor(v,16,64); \
  v += __shfl_xor(v,8,64); v += __shfl_xor(v,4,64); v += __shfl_xor(v,2,64); \
  v += __shfl_xor(v,1,64); }

#define G16(M) M(0) M(1) M(2) M(3) M(4) M(5) M(6) M(7) M(8) M(9) M(10) M(11) \
  M(12) M(13) M(14) M(15)

// dopri5 coefficients
#define CA0 ((float)(44.0/45.0))
#define CA1 ((float)(-56.0/15.0))
#define CA2 ((float)(32.0/9.0))
#define CB0 ((float)(19372.0/6561.0))
#define CB1 ((float)(-25360.0/2187.0))
#define CB2 ((float)(64448.0/6561.0))
#define CB3 ((float)(-212.0/729.0))
#define CC0 ((float)(9017.0/3168.0))
#define CC1 ((float)(-355.0/33.0))
#define CC2 ((float)(46732.0/5247.0))
#define CC3 ((float)(49.0/176.0))
#define CC4 ((float)(-5103.0/18656.0))
#define BW0 ((float)(35.0/384.0))
#define BW2 ((float)(500.0/1113.0))
#define BW3 ((float)(125.0/192.0))
#define BW4 ((float)(-2187.0/6784.0))
#define BW5 ((float)(11.0/84.0))

// TPB=256: VGPR cap = 65536/TPB = 256 (empirical law, r1-r12). One block per
// sample, 4 waves = 1 wave/SIMD (grid 128 < 256 CUs, nothing lost).
//  - W1 FULLY in registers: 128 u32 f16-pairs (thread = 32 rows x 8 cols).
//    H-phase does zero weight LDS traffic.
//  - W2 in LDS (r12's validated swizzle), 32 b128/thread/eval; only 4 waves
//    share the DS pipe -> ~166 wave-DS/CU/eval vs r12's 204+conflicts.
//  - every operand b128 feeds 8 fdot2 (was 4) -> x/a reads halve.
//  - aPKp stride-20 padded layout (pair p at word p + 4*(p>>4)) -> 2-way max.
//  - all-DPP reductions; k-history f16-packed; 2 barriers/eval.
__global__ __launch_bounds__(TPB, 1) void vi_node_kernel(
    const float* __restrict__ x0, const float* __restrict__ W1,
    const float* __restrict__ b1, const float* __restrict__ u1,
    const float* __restrict__ W2, const float* __restrict__ b2,
    const int* __restrict__ nsp, float* __restrict__ out, int nB)
{
    const int s  = blockIdx.x;
    const int t  = threadIdx.x;
    const int l  = t & 63;
    const int w  = t >> 6;       // wave 0..3
    const int rg  = t & 3;       // H rows 32rg..32rg+31 (of 128)
    const int cg  = t >> 2;      // H cols 8cg..8cg+7 (of 512)
    const int rg4 = t & 15;      // P rows 32rg4..32rg4+31 (of 512)
    const int jg  = t >> 4;      // P cols 8jg..8jg+7 (of 128)

    __shared__ __align__(16) unsigned BIG[32768];  // 128 KB: W1 staging, then W2
    __shared__ __align__(16) unsigned xsPK[64];    // x f16 pairs
    __shared__ __align__(16) unsigned aPKp[320];   // acts, pair p at p+4*(p>>4)
    __shared__ float redA[4], redB[4], sqred[2];

    // ---- 1) stage W1 as f16 row-pairs (coalesced) ----
    for (int idx = t; idx < 32768; idx += TPB) {
        const int rp = idx >> 9, c = idx & 511;
        BIG[idx] = pk2h(W1[(2 * rp) * 512 + c], W1[(2 * rp + 1) * 512 + c]);
    }
    __syncthreads();

    // ---- 2) W1 regs: w1_{i}_{m} = rows 2(16rg+i),+1 of col 8cg+m ----
#define DECLW1(i) unsigned w1_##i##_0, w1_##i##_1, w1_##i##_2, w1_##i##_3, \
                           w1_##i##_4, w1_##i##_5, w1_##i##_6, w1_##i##_7;
    G16(DECLW1)
#define LW1(i) { const uint4 va = *(const uint4*)&BIG[((16*rg+(i))<<9) + 8*cg]; \
                 const uint4 vb = *(const uint4*)&BIG[((16*rg+(i))<<9) + 8*cg + 4]; \
    w1_##i##_0 = va.x; w1_##i##_1 = va.y; w1_##i##_2 = va.z; w1_##i##_3 = va.w; \
    w1_##i##_4 = vb.x; w1_##i##_5 = vb.y; w1_##i##_6 = vb.z; w1_##i##_7 = vb.w; }
    G16(LW1)

    // wdiag_m over this thread's 32 rows; RED4 -> full 128-row column sums
    float wd0=0.f,wd1=0.f,wd2=0.f,wd3=0.f,wd4=0.f,wd5=0.f,wd6=0.f,wd7=0.f;
#define WDI(i) { const int r2_ = 2 * (16 * rg + (i)); \
    wd0 = FDOT2(w1_##i##_0, pk2h(W2[(8*cg+0)*128+r2_], W2[(8*cg+0)*128+r2_+1]), wd0); \
    wd1 = FDOT2(w1_##i##_1, pk2h(W2[(8*cg+1)*128+r2_], W2[(8*cg+1)*128+r2_+1]), wd1); \
    wd2 = FDOT2(w1_##i##_2, pk2h(W2[(8*cg+2)*128+r2_], W2[(8*cg+2)*128+r2_+1]), wd2); \
    wd3 = FDOT2(w1_##i##_3, pk2h(W2[(8*cg+3)*128+r2_], W2[(8*cg+3)*128+r2_+1]), wd3); \
    wd4 = FDOT2(w1_##i##_4, pk2h(W2[(8*cg+4)*128+r2_], W2[(8*cg+4)*128+r2_+1]), wd4); \
    wd5 = FDOT2(w1_##i##_5, pk2h(W2[(8*cg+5)*128+r2_], W2[(8*cg+5)*128+r2_+1]), wd5); \
    wd6 = FDOT2(w1_##i##_6, pk2h(W2[(8*cg+6)*128+r2_], W2[(8*cg+6)*128+r2_+1]), wd6); \
    wd7 = FDOT2(w1_##i##_7, pk2h(W2[(8*cg+7)*128+r2_], W2[(8*cg+7)*128+r2_+1]), wd7); }
    G16(WDI)
    RED4(wd0) RED4(wd1) RED4(wd2) RED4(wd3)
    RED4(wd4) RED4(wd5) RED4(wd6) RED4(wd7)

    __syncthreads();   // all W1-staging reads done before overwrite

    // ---- 3) stage W2 swizzled (col c at c^((rp>>4)&7)<<2, r12-validated) ----
    for (int idx = t; idx < 32768; idx += TPB) {
        const int rp = idx >> 7, c = idx & 127;
        BIG[(rp << 7) + (c ^ (((rp >> 4) & 7) << 2))] =
            pk2h(W2[(2 * rp) * 128 + c], W2[(2 * rp + 1) * 128 + c]);
    }
    if (t < 64) xsPK[t] = pk2h(x0[s * 128 + 2 * t], x0[s * 128 + 2 * t + 1]);
    if (t < 128) {
        float xv = x0[s * 128 + t];
        float sq = xv * xv;
        RED64(sq)
        if (l == 0) sqred[w] = sq;
    }

    // packed biases
    const unsigned b1p0 = pk2h(b1[8*cg+0], b1[8*cg+1]);
    const unsigned b1p1 = pk2h(b1[8*cg+2], b1[8*cg+3]);
    const unsigned b1p2 = pk2h(b1[8*cg+4], b1[8*cg+5]);
    const unsigned b1p3 = pk2h(b1[8*cg+6], b1[8*cg+7]);
    const unsigned u1p0 = pk2h(u1[8*cg+0], u1[8*cg+1]);
    const unsigned u1p1 = pk2h(u1[8*cg+2], u1[8*cg+3]);
    const unsigned u1p2 = pk2h(u1[8*cg+4], u1[8*cg+5]);
    const unsigned u1p3 = pk2h(u1[8*cg+6], u1[8*cg+7]);
    const unsigned b2p0 = pk2h(b2[8*jg+0], b2[8*jg+1]);
    const unsigned b2p1 = pk2h(b2[8*jg+2], b2[8*jg+3]);
    const unsigned b2p2 = pk2h(b2[8*jg+4], b2[8*jg+5]);
    const unsigned b2p3 = pk2h(b2[8*jg+6], b2[8*jg+7]);

    // state: 8 cols per thread, replicated x16 across the jg group
    float xc0 = x0[s*128+8*jg+0], xc1 = x0[s*128+8*jg+1];
    float xc2 = x0[s*128+8*jg+2], xc3 = x0[s*128+8*jg+3];
    float xc4 = x0[s*128+8*jg+4], xc5 = x0[s*128+8*jg+5];
    float xc6 = x0[s*128+8*jg+6], xc7 = x0[s*128+8*jg+7];
    float yc0=xc0,yc1=xc1,yc2=xc2,yc3=xc3,yc4=xc4,yc5=xc5,yc6=xc6,yc7=xc7;
    unsigned k0a=0,k0b=0,k0c=0,k0d=0, k1a=0,k1b=0,k1c=0,k1d=0,
             k2a=0,k2b=0,k2c=0,k2d=0, k3a=0,k3b=0,k3c=0,k3d=0,
             k4a=0,k4b=0,k4c=0,k4d=0;
    float tr_loc = 0.f, dot_loc = 0.f;

    const int ns = nsp[0];
    const float dt = 1.f / (float)ns;

    const int awrd = 4*cg + 4*(cg>>2);                         // aPKp write base
    const int off0 = ((16*rg4)<<7) + (((2*jg  ) ^ (rg4 & 7))<<2);
    const int off1 = ((16*rg4)<<7) + (((2*jg+1) ^ (rg4 & 7))<<2);

    __syncthreads();

#define HI(i, XP) { \
    a0 = FDOT2(w1_##i##_0,(XP),a0); a1 = FDOT2(w1_##i##_1,(XP),a1); \
    a2 = FDOT2(w1_##i##_2,(XP),a2); a3 = FDOT2(w1_##i##_3,(XP),a3); \
    a4 = FDOT2(w1_##i##_4,(XP),a4); a5 = FDOT2(w1_##i##_5,(XP),a5); \
    a6 = FDOT2(w1_##i##_6,(XP),a6); a7 = FDOT2(w1_##i##_7,(XP),a7); }

#define PI(i, AP) { \
    const uint4 wa = *(const uint4*)&BIG[off0 + ((i)<<7)]; \
    const uint4 wb = *(const uint4*)&BIG[off1 + ((i)<<7)]; \
    p0 = FDOT2(wa.x,(AP),p0); p1 = FDOT2(wa.y,(AP),p1); \
    p2 = FDOT2(wa.z,(AP),p2); p3 = FDOT2(wa.w,(AP),p3); \
    p4 = FDOT2(wb.x,(AP),p4); p5 = FDOT2(wb.y,(AP),p5); \
    p6 = FDOT2(wb.z,(AP),p6); p7 = FDOT2(wb.w,(AP),p7); }

#define UNPK(st) const float K##st##_0=UPa(k##st##a), K##st##_1=UPb(k##st##a), \
    K##st##_2=UPa(k##st##b), K##st##_3=UPb(k##st##b), K##st##_4=UPa(k##st##c), \
    K##st##_5=UPb(k##st##c), K##st##_6=UPa(k##st##d), K##st##_7=UPb(k##st##d);

// per-stage x updates (ST5 also commits y)
#define ST0(m) { xc##m = fmaf(dt, 0.2f * dx##m, yc##m); }
#define ST1(m) { xc##m = yc##m + dt*(0.075f*K0_##m + 0.225f*dx##m); }
#define ST2(m) { xc##m = yc##m + dt*(CA0*K0_##m + CA1*K1_##m + CA2*dx##m); }
#define ST3(m) { xc##m = yc##m + dt*(CB0*K0_##m + CB1*K1_##m + CB2*K2_##m + CB3*dx##m); }
#define ST4(m) { xc##m = yc##m + dt*(CC0*K0_##m + CC1*K1_##m + CC2*K2_##m + CC3*K3_##m + CC4*dx##m); }
#define ST5(m) { const float xn_ = yc##m + dt*(BW0*K0_##m + BW2*K2_##m + BW3*K3_##m + BW4*K4_##m + BW5*dx##m); \
                 xc##m = xn_; yc##m = xn_; }

// One RHS eval + state advance. 2 barriers.
#define EVAL(CW, TVAL, KSTORE, STM)                                            \
    {                                                                          \
        float a0=0.f,a1=0.f,a2=0.f,a3=0.f,a4=0.f,a5=0.f,a6=0.f,a7=0.f;         \
        { const uint4 xq0 = *(const uint4*)&xsPK[16*rg];                       \
          const uint4 xq1 = *(const uint4*)&xsPK[16*rg+4];                     \
          const uint4 xq2 = *(const uint4*)&xsPK[16*rg+8];                     \
          const uint4 xq3 = *(const uint4*)&xsPK[16*rg+12];                    \
          HI(0,xq0.x) HI(1,xq0.y) HI(2,xq0.z) HI(3,xq0.w)                      \
          HI(4,xq1.x) HI(5,xq1.y) HI(6,xq1.z) HI(7,xq1.w)                      \
          HI(8,xq2.x) HI(9,xq2.y) HI(10,xq2.z) HI(11,xq2.w)                    \
          HI(12,xq3.x) HI(13,xq3.y) HI(14,xq3.z) HI(15,xq3.w) }                \
        RED4(a0) RED4(a1) RED4(a2) RED4(a3)                                    \
        RED4(a4) RED4(a5) RED4(a6) RED4(a7)                                    \
        if (rg == 0) {                                                         \
            const float tv_ = (TVAL);                                          \
            const float h0_ = fmaf(tv_, UPa(u1p0), UPa(b1p0)) + a0;            \
            const float h1_ = fmaf(tv_, UPb(u1p0), UPb(b1p0)) + a1;            \
            const float h2_ = fmaf(tv_, UPa(u1p1), UPa(b1p1)) + a2;            \
            const float h3_ = fmaf(tv_, UPb(u1p1), UPb(b1p1)) + a3;            \
            const float h4_ = fmaf(tv_, UPa(u1p2), UPa(b1p2)) + a4;            \
            const float h5_ = fmaf(tv_, UPb(u1p2), UPb(b1p2)) + a5;            \
            const float h6_ = fmaf(tv_, UPa(u1p3), UPa(b1p3)) + a6;            \
            const float h7_ = fmaf(tv_, UPb(u1p3), UPb(b1p3)) + a7;            \
            const float t0_ = 1.f - 2.f / (__expf(2.f * h0_) + 1.f);           \
            const float t1_ = 1.f - 2.f / (__expf(2.f * h1_) + 1.f);           \
            const float t2_ = 1.f - 2.f / (__expf(2.f * h2_) + 1.f);           \
            const float t3_ = 1.f - 2.f / (__expf(2.f * h3_) + 1.f);           \
            const float t4_ = 1.f - 2.f / (__expf(2.f * h4_) + 1.f);           \
            const float t5_ = 1.f - 2.f / (__expf(2.f * h5_) + 1.f);           \
            const float t6_ = 1.f - 2.f / (__expf(2.f * h6_) + 1.f);           \
            const float t7_ = 1.f - 2.f / (__expf(2.f * h7_) + 1.f);           \
            *(uint4*)&aPKp[awrd] = make_uint4(pk2h(t0_,t1_), pk2h(t2_,t3_),    \
                                              pk2h(t4_,t5_), pk2h(t6_,t7_));   \
            tr_loc = fmaf((CW),                                                \
                ((fmaf(-t0_,t0_,1.f)*wd0 + fmaf(-t1_,t1_,1.f)*wd1)             \
               + (fmaf(-t2_,t2_,1.f)*wd2 + fmaf(-t3_,t3_,1.f)*wd3))            \
              + ((fmaf(-t4_,t4_,1.f)*wd4 + fmaf(-t5_,t5_,1.f)*wd5)             \
               + (fmaf(-t6_,t6_,1.f)*wd6 + fmaf(-t7_,t7_,1.f)*wd7)), tr_loc);  \
        }                                                                      \
        __syncthreads();                          /* B1: aPKp ready */         \
        float p0=0.f,p1=0.f,p2=0.f,p3=0.f,p4=0.f,p5=0.f,p6=0.f,p7=0.f;         \
        { const uint4 aq0 = *(const uint4*)&aPKp[20*rg4];                      \
          const uint4 aq1 = *(const uint4*)&aPKp[20*rg4+4];                    \
          const uint4 aq2 = *(const uint4*)&aPKp[20*rg4+8];                    \
          const uint4 aq3 = *(const uint4*)&aPKp[20*rg4+12];                   \
          PI(0,aq0.x) PI(1,aq0.y) PI(2,aq0.z) PI(3,aq0.w)                      \
          PI(4,aq1.x) PI(5,aq1.y) PI(6,aq1.z) PI(7,aq1.w)                      \
          PI(8,aq2.x) PI(9,aq2.y) PI(10,aq2.z) PI(11,aq2.w)                    \
          PI(12,aq3.x) PI(13,aq3.y) PI(14,aq3.z) PI(15,aq3.w) }                \
        RED16(p0) RED16(p1) RED16(p2) RED16(p3)                                \
        RED16(p4) RED16(p5) RED16(p6) RED16(p7)                                \
        const float dx0 = p0 + UPa(b2p0), dx1 = p1 + UPb(b2p0);                \
        const float dx2 = p2 + UPa(b2p1), dx3 = p3 + UPb(b2p1);                \
        const float dx4 = p4 + UPa(b2p2), dx5 = p5 + UPb(b2p2);                \
        const float dx6 = p6 + UPa(b2p3), dx7 = p7 + UPb(b2p3);                \
        dot_loc = fmaf((CW), ((xc0*dx0 + xc1*dx1) + (xc2*dx2 + xc3*dx3))       \
                           + ((xc4*dx4 + xc5*dx5) + (xc6*dx6 + xc7*dx7)),      \
                  dot_loc);                                                    \
        KSTORE;                                                                \
        UNPK(0) UNPK(1) UNPK(2) UNPK(3) UNPK(4)                                \
        STM(0) STM(1) STM(2) STM(3) STM(4) STM(5) STM(6) STM(7)                \
        if (rg4 == 0)                                                          \
            *(uint4*)&xsPK[4*jg] = make_uint4(pk2h(xc0,xc1), pk2h(xc2,xc3),    \
                                              pk2h(xc4,xc5), pk2h(xc6,xc7));   \
        __syncthreads();                          /* B2: xsPK ready */         \
    }

    for (int n = 0; n < ns; ++n) {
        const float tn = (float)n;

        EVAL(BW0, tn * dt,
             (k0a=pk2h(dx0,dx1), k0b=pk2h(dx2,dx3), k0c=pk2h(dx4,dx5), k0d=pk2h(dx6,dx7)),
             ST0)
        EVAL(0.0f, (tn + 0.2f) * dt,
             (k1a=pk2h(dx0,dx1), k1b=pk2h(dx2,dx3), k1c=pk2h(dx4,dx5), k1d=pk2h(dx6,dx7)),
             ST1)
        EVAL(BW2, (tn + 0.3f) * dt,
             (k2a=pk2h(dx0,dx1), k2b=pk2h(dx2,dx3), k2c=pk2h(dx4,dx5), k2d=pk2h(dx6,dx7)),
             ST2)
        EVAL(BW3, (tn + 0.8f) * dt,
             (k3a=pk2h(dx0,dx1), k3b=pk2h(dx2,dx3), k3c=pk2h(dx4,dx5), k3d=pk2h(dx6,dx7)),
             ST3)
        EVAL(BW4, (tn + (float)(8.0/9.0)) * dt,
             (k4a=pk2h(dx0,dx1), k4b=pk2h(dx2,dx3), k4c=pk2h(dx4,dx5), k4d=pk2h(dx6,dx7)),
             ST4)
        EVAL(BW5, (tn + 1.0f) * dt, ((void)0), ST5)
    }

    // ---- final reductions: tr (rg==0 lanes, each cg once), dot (x16 repl) ----
    {
        float tv = tr_loc;  RED64(tv)  if (l == 0) redA[w] = tv;
        float dv = dot_loc; RED64(dv)  if (l == 0) redB[w] = dv;
    }
    __syncthreads();

    // ---- outputs: z (B,D) | log_px (B) | kl (B) ----
    if (rg4 == 0) {
        out[s*128 + 8*jg + 0] = yc0; out[s*128 + 8*jg + 1] = yc1;
        out[s*128 + 8*jg + 2] = yc2; out[s*128 + 8*jg + 3] = yc3;
        out[s*128 + 8*jg + 4] = yc4; out[s*128 + 8*jg + 5] = yc5;
        out[s*128 + 8*jg + 6] = yc6; out[s*128 + 8*jg + 7] = yc7;
    }
    if (t == 0) {
        float TRs = (redA[0] + redA[1]) + (redA[2] + redA[3]);
        float DOs = (redB[0] + redB[1]) + (redB[2] + redB[3]);
        const float TR = TRs * dt;                  // each col counted once
        const float DO = DOs * dt * (1.f / 16.f);   // 16x lane replication
        const float LOG2PI = 1.8378770664093454f;
        float lpx0 = -0.5f * (sqred[0] + sqred[1]) - 0.5f * 128.f * LOG2PI;
        out[nB * 128 + s]      = lpx0 - TR;
        out[nB * 128 + nB + s] = DO - TR;
    }
}

extern "C" void kernel_launch(void* const* d_in, const int* in_sizes, int n_in,
                              void* d_out, int out_size, void* d_ws, size_t ws_size,
                              hipStream_t stream) {
    const float* x0 = (const float*)d_in[0];
    const float* W1 = (const float*)d_in[1];
    const float* b1 = (const float*)d_in[2];
    const float* u1 = (const float*)d_in[3];
    const float* W2 = (const float*)d_in[4];
    const float* b2 = (const float*)d_in[5];
    const int*  nsp = (const int*)d_in[6];
    float* out = (float*)d_out;
    const int nB = in_sizes[0] / 128;   // 128 samples

    hipLaunchKernelGGL(vi_node_kernel, dim3(nB), dim3(TPB), 0, stream,
                       x0, W1, b1, u1, W2, b2, nsp, out, nB);
}